// Round 3
// baseline (26496.329 us; speedup 1.0000x reference)
//
#include <hip/hip_runtime.h>
#include <cstdint>
#include <cstddef>

// ---------------------------------------------------------------------------
// GumbelRNNGenerator persistent-kernel v2.
// B=128, NOISE=128, H=512, V=5000, T=128 sequential steps, all fp32.
// 512 blocks x 256 threads (2 blocks/CU -> 8 waves/CU), flag-array barrier.
// ---------------------------------------------------------------------------
#define B_SZ 128
#define NOISE_SZ 128
#define H 512
#define V_SZ 5000
#define BN_EPS 1e-5f
#define NBLK 512
#define NTHR 256

// workspace offsets (in floats)
#define XBUF_OFF 0            // [128][512] lrelu(emb[prev]) raw (pre-BN)
#define H_OFF    65536        // [128][512] hidden state
#define O_OFF    131072       // [128][512] bn(lrelu(h)) / setup scratch si_z
#define SIX_OFF  196608       // [128][512] bn(concat)[:, :512]; aliases zbn in setup
#define GI_OFF   262144       // [128][1536]
#define GH_OFF   458752       // [128][1536]
#define GIZ_OFF  655360       // [128][1536] si_z @ W_ih[:,512:]^T + b_ih
#define BAR_OFF  851968       // barrier state (uint32 area)

// ------------------------------- Threefry ---------------------------------
__device__ __forceinline__ uint32_t rotl32(uint32_t v, int r) {
  return (v << r) | (v >> (32 - r));
}

__device__ __forceinline__ void threefry2x32(uint32_t k0, uint32_t k1,
                                             uint32_t x0, uint32_t x1,
                                             uint32_t& o0, uint32_t& o1) {
  uint32_t k2 = k0 ^ k1 ^ 0x1BD11BDAu;
  x0 += k0; x1 += k1;
#define TFR(r) { x0 += x1; x1 = rotl32(x1, (r)); x1 ^= x0; }
  TFR(13) TFR(15) TFR(26) TFR(6)
  x0 += k1; x1 += k2 + 1u;
  TFR(17) TFR(29) TFR(16) TFR(24)
  x0 += k2; x1 += k0 + 2u;
  TFR(13) TFR(15) TFR(26) TFR(6)
  x0 += k0; x1 += k1 + 3u;
  TFR(17) TFR(29) TFR(16) TFR(24)
  x0 += k1; x1 += k2 + 4u;
  TFR(13) TFR(15) TFR(26) TFR(6)
  x0 += k2; x1 += k0 + 5u;
#undef TFR
  o0 = x0; o1 = x1;
}

// compile-time subkey chain: jax.random.key(42), partitionable fold-in split
struct U2 { uint32_t a, b; };
constexpr U2 tf_c(uint32_t k0, uint32_t k1, uint32_t x0, uint32_t x1) {
  uint32_t k2 = k0 ^ k1 ^ 0x1BD11BDAu;
  x0 += k0; x1 += k1;
#define TFRC(r) { x0 += x1; x1 = (uint32_t)((x1 << (r)) | (x1 >> (32 - (r)))); x1 ^= x0; }
  TFRC(13) TFRC(15) TFRC(26) TFRC(6)
  x0 += k1; x1 += k2 + 1u;
  TFRC(17) TFRC(29) TFRC(16) TFRC(24)
  x0 += k2; x1 += k0 + 2u;
  TFRC(13) TFRC(15) TFRC(26) TFRC(6)
  x0 += k0; x1 += k1 + 3u;
  TFRC(17) TFRC(29) TFRC(16) TFRC(24)
  x0 += k1; x1 += k2 + 4u;
  TFRC(13) TFRC(15) TFRC(26) TFRC(6)
  x0 += k2; x1 += k0 + 5u;
#undef TFRC
  return U2{x0, x1};
}

struct SubKeys { uint32_t v[512]; };
constexpr SubKeys make_subkeys() {
  SubKeys s{};
  uint32_t k0 = 0u, k1 = 42u;
  for (int t = 0; t < 256; ++t) {
    U2 nk = tf_c(k0, k1, 0u, 0u);   // new key
    U2 sb = tf_c(k0, k1, 0u, 1u);   // subkey
    s.v[2 * t] = sb.a; s.v[2 * t + 1] = sb.b;
    k0 = nk.a; k1 = nk.b;
  }
  return s;
}
__device__ __constant__ SubKeys SUBK = make_subkeys();

__device__ __forceinline__ float lrelu_(float x) { return x >= 0.f ? x : 0.2f * x; }
__device__ __forceinline__ float sigmoidf_(float x) {
  return (x >= 0.f) ? 1.f / (1.f + expf(-x)) : expf(x) / (1.f + expf(x));
}

// --------------------------- grid barrier (flags) --------------------------
// bw[0] = generation (own line); flags[i] at bw[16 + i*16] (64B spread).
// Arrival: one atomic-exchange per block (parallel, no serialized RMW chain).
// Block 0 = master: 256 threads poll 511 flags concurrently, then release.
__device__ __forceinline__ void gridbar(uint32_t* bw, uint32_t target) {
  __syncthreads();
  const int tid = threadIdx.x;
  if (blockIdx.x == 0) {
    for (int f = 1 + tid; f < NBLK; f += NTHR) {
      while (__hip_atomic_load(&bw[16 + f * 16], __ATOMIC_RELAXED,
                               __HIP_MEMORY_SCOPE_AGENT) < target)
        __builtin_amdgcn_s_sleep(1);
    }
    __syncthreads();
    if (tid == 0) {
      __threadfence();   // release: write back our L2 (stage outputs)
      __hip_atomic_store(&bw[0], target, __ATOMIC_RELAXED, __HIP_MEMORY_SCOPE_AGENT);
      __threadfence();   // acquire: invalidate so we see remote stage outputs
    }
  } else {
    if (tid == 0) {
      __threadfence();   // release
      (void)__hip_atomic_exchange(&bw[16 + blockIdx.x * 16], target,
                                  __ATOMIC_RELAXED, __HIP_MEMORY_SCOPE_AGENT);
      while (__hip_atomic_load(&bw[0], __ATOMIC_RELAXED,
                               __HIP_MEMORY_SCOPE_AGENT) < target)
        __builtin_amdgcn_s_sleep(1);
      __threadfence();   // acquire
    }
  }
  __syncthreads();
}

// ------------------------- GEMM 16x64 tile ---------------------------------
// C[m0:+16, n0:+64] = A[16xK]@W[64xK]^T + (full?full:bias), optional lrelu.
__device__ __forceinline__ void gemm16x64(
    const float* __restrict__ A, int lda,
    const float* __restrict__ W, int ldw, int K,
    int m0, int n0,
    const float* __restrict__ bias,
    const float* __restrict__ full, int fullld,
    bool relu,
    float* __restrict__ C, int ldc,
    float* smem) {
  float* As = smem;          // [32][17]
  float* Ws = smem + 544;    // [32][68]
  const int tid = threadIdx.x;
  const int tm = tid >> 4, tn = tid & 15;   // 1 row x 4 cols per thread
  const int amr = tid >> 3, aq = tid & 7;   // A stager (tid<128)
  const int wnr = tid >> 2, wq = tid & 3;   // W stager
  float acc[4] = {0.f, 0.f, 0.f, 0.f};
  for (int k0 = 0; k0 < K; k0 += 32) {
    if (tid < 128) {
      const float4 av = *(const float4*)&A[(size_t)(m0 + amr) * lda + k0 + aq * 4];
      As[(aq * 4 + 0) * 17 + amr] = av.x;
      As[(aq * 4 + 1) * 17 + amr] = av.y;
      As[(aq * 4 + 2) * 17 + amr] = av.z;
      As[(aq * 4 + 3) * 17 + amr] = av.w;
    }
    const float4 w0 = *(const float4*)&W[(size_t)(n0 + wnr) * ldw + k0 + wq * 4];
    const float4 w1 = *(const float4*)&W[(size_t)(n0 + wnr) * ldw + k0 + 16 + wq * 4];
    Ws[(wq * 4 + 0) * 68 + wnr] = w0.x;
    Ws[(wq * 4 + 1) * 68 + wnr] = w0.y;
    Ws[(wq * 4 + 2) * 68 + wnr] = w0.z;
    Ws[(wq * 4 + 3) * 68 + wnr] = w0.w;
    Ws[(16 + wq * 4 + 0) * 68 + wnr] = w1.x;
    Ws[(16 + wq * 4 + 1) * 68 + wnr] = w1.y;
    Ws[(16 + wq * 4 + 2) * 68 + wnr] = w1.z;
    Ws[(16 + wq * 4 + 3) * 68 + wnr] = w1.w;
    __syncthreads();
#pragma unroll
    for (int kk = 0; kk < 32; ++kk) {
      const float a = As[kk * 17 + tm];
      const float4 b4 = *(const float4*)&Ws[kk * 68 + tn * 4];
      acc[0] = fmaf(a, b4.x, acc[0]);
      acc[1] = fmaf(a, b4.y, acc[1]);
      acc[2] = fmaf(a, b4.z, acc[2]);
      acc[3] = fmaf(a, b4.w, acc[3]);
    }
    __syncthreads();
  }
  const int m = m0 + tm;
#pragma unroll
  for (int j = 0; j < 4; ++j) {
    const int n = n0 + tn * 4 + j;
    float v = acc[j] + (full ? full[(size_t)m * fullld + n] : bias[n]);
    if (relu) v = lrelu_(v);
    C[(size_t)m * ldc + n] = v;
  }
}

// ------------------------- GEMM 16x32 tile ---------------------------------
__device__ __forceinline__ void gemm16x32(
    const float* __restrict__ A, int lda,
    const float* __restrict__ W, int ldw, int K,
    int m0, int n0,
    const float* __restrict__ bias,
    const float* __restrict__ full, int fullld,
    float* __restrict__ C, int ldc,
    float* smem) {
  float* As = smem;          // [32][17]
  float* Ws = smem + 544;    // [32][36]
  const int tid = threadIdx.x;
  const int tm = tid >> 4, tn = tid & 15;   // 1 row x 2 cols per thread
  const int amr = tid >> 3, aq = tid & 7;
  const int wnr = tid >> 3, wq = tid & 7;   // 32 rows x 1 quad
  float acc[2] = {0.f, 0.f};
  for (int k0 = 0; k0 < K; k0 += 32) {
    if (tid < 128) {
      const float4 av = *(const float4*)&A[(size_t)(m0 + amr) * lda + k0 + aq * 4];
      As[(aq * 4 + 0) * 17 + amr] = av.x;
      As[(aq * 4 + 1) * 17 + amr] = av.y;
      As[(aq * 4 + 2) * 17 + amr] = av.z;
      As[(aq * 4 + 3) * 17 + amr] = av.w;
    }
    const float4 w0 = *(const float4*)&W[(size_t)(n0 + wnr) * ldw + k0 + wq * 4];
    Ws[(wq * 4 + 0) * 36 + wnr] = w0.x;
    Ws[(wq * 4 + 1) * 36 + wnr] = w0.y;
    Ws[(wq * 4 + 2) * 36 + wnr] = w0.z;
    Ws[(wq * 4 + 3) * 36 + wnr] = w0.w;
    __syncthreads();
#pragma unroll
    for (int kk = 0; kk < 32; ++kk) {
      const float a = As[kk * 17 + tm];
      const float2 b2 = *(const float2*)&Ws[kk * 36 + tn * 2];
      acc[0] = fmaf(a, b2.x, acc[0]);
      acc[1] = fmaf(a, b2.y, acc[1]);
    }
    __syncthreads();
  }
  const int m = m0 + tm;
#pragma unroll
  for (int j = 0; j < 2; ++j) {
    const int n = n0 + tn * 2 + j;
    const float v = acc[j] + (full ? full[(size_t)m * fullld + n] : bias[n]);
    C[(size_t)m * ldc + n] = v;
  }
}

// -------------------- GEMM 16x80 logits + gumbel epilogue ------------------
// Writes y = ((o@W^T + b) + gumbel)/temp straight into out[(m*T + t)*V + n].
__device__ __forceinline__ void gemm16x80_logits(
    const float* __restrict__ A, const float* __restrict__ W,
    const float* __restrict__ bias, int m0, int n0,
    float* __restrict__ out, int t, int T,
    const float* __restrict__ temp_ptr, float* smem) {
  float* As = smem;          // [32][17]
  float* Ws = smem + 544;    // [32][84]
  const int tid = threadIdx.x;
  const int tm = tid >> 4, tn = tid & 15;   // 1 row x (4+1) cols per thread
  const int amr = tid >> 3, aq = tid & 7;
  float acc[5] = {0.f, 0.f, 0.f, 0.f, 0.f};
  for (int k0 = 0; k0 < 512; k0 += 32) {
    if (tid < 128) {
      const float4 av = *(const float4*)&A[(size_t)(m0 + amr) * 512 + k0 + aq * 4];
      As[(aq * 4 + 0) * 17 + amr] = av.x;
      As[(aq * 4 + 1) * 17 + amr] = av.y;
      As[(aq * 4 + 2) * 17 + amr] = av.z;
      As[(aq * 4 + 3) * 17 + amr] = av.w;
    }
    // stage 80 W rows x 32 k: 640 float4 units
    for (int i = tid; i < 640; i += NTHR) {
      const int row = i >> 3, q = i & 7;
      float4 w = {0.f, 0.f, 0.f, 0.f};
      if (n0 + row < V_SZ)
        w = *(const float4*)&W[(size_t)(n0 + row) * 512 + k0 + q * 4];
      Ws[(q * 4 + 0) * 84 + row] = w.x;
      Ws[(q * 4 + 1) * 84 + row] = w.y;
      Ws[(q * 4 + 2) * 84 + row] = w.z;
      Ws[(q * 4 + 3) * 84 + row] = w.w;
    }
    __syncthreads();
#pragma unroll
    for (int kk = 0; kk < 32; ++kk) {
      const float a = As[kk * 17 + tm];
      const float4 b4 = *(const float4*)&Ws[kk * 84 + tn * 4];
      const float b1 = Ws[kk * 84 + 64 + tn];
      acc[0] = fmaf(a, b4.x, acc[0]);
      acc[1] = fmaf(a, b4.y, acc[1]);
      acc[2] = fmaf(a, b4.z, acc[2]);
      acc[3] = fmaf(a, b4.w, acc[3]);
      acc[4] = fmaf(a, b1,   acc[4]);
    }
    __syncthreads();
  }
  const float temp = temp_ptr[0];
  const uint32_t sk0 = SUBK.v[2 * t], sk1 = SUBK.v[2 * t + 1];
  const int m = m0 + tm;
  float* rowp = out + ((size_t)m * T + t) * V_SZ;
#pragma unroll
  for (int j = 0; j < 5; ++j) {
    const int n = (j < 4) ? (n0 + tn * 4 + j) : (n0 + 64 + tn);
    if (n < V_SZ) {
      const float logit = acc[j] + bias[n];
      uint32_t r0, r1;
      threefry2x32(sk0, sk1, 0u, (uint32_t)(m * V_SZ + n), r0, r1);
      const uint32_t bits = r0 ^ r1;
      const float f = __uint_as_float((bits >> 9) | 0x3f800000u) - 1.0f;
      const float u = fmaxf(1e-20f, f + 1e-20f);
      const float gum = -logf(-logf(u));
      rowp[n] = (logit + gum) / temp;
    }
  }
}

// ------------------- BN over batch, 8 cols per block -----------------------
__device__ __forceinline__ void bn8(const float* __restrict__ in,
                                    const float* __restrict__ g,
                                    const float* __restrict__ be,
                                    float* __restrict__ outp,
                                    float* __restrict__ out2, int c0) {
  const int col = c0 + (threadIdx.x >> 5);
  const int r = threadIdx.x & 31;
  float x0 = in[(size_t)r * H + col];
  float x1 = in[(size_t)(r + 32) * H + col];
  float x2 = in[(size_t)(r + 64) * H + col];
  float x3 = in[(size_t)(r + 96) * H + col];
  float s = x0 + x1 + x2 + x3;
#pragma unroll
  for (int m = 16; m; m >>= 1) s += __shfl_xor(s, m);
  const float mean = s * (1.f / 128.f);
  const float d0 = x0 - mean, d1 = x1 - mean, d2 = x2 - mean, d3 = x3 - mean;
  float q = d0 * d0 + d1 * d1 + d2 * d2 + d3 * d3;
#pragma unroll
  for (int m = 16; m; m >>= 1) q += __shfl_xor(q, m);
  const float v = q * (1.f / 128.f);
  const float sd = sqrtf(v + BN_EPS);
  const float gc = g[col], bc = be[col];
  const float y0 = gc * d0 / sd + bc;
  const float y1 = gc * d1 / sd + bc;
  const float y2 = gc * d2 / sd + bc;
  const float y3 = gc * d3 / sd + bc;
  outp[(size_t)r * H + col] = y0;
  outp[(size_t)(r + 32) * H + col] = y1;
  outp[(size_t)(r + 64) * H + col] = y2;
  outp[(size_t)(r + 96) * H + col] = y3;
  if (out2) {
    out2[(size_t)r * H + col] = y0;
    out2[(size_t)(r + 32) * H + col] = y1;
    out2[(size_t)(r + 64) * H + col] = y2;
    out2[(size_t)(r + 96) * H + col] = y3;
  }
}

// ----------------- GRU gates + h update + BN(lrelu(h)) -> o ----------------
__device__ __forceinline__ void gru8(const float* __restrict__ gi,
                                     const float* __restrict__ gh,
                                     float* __restrict__ h,
                                     const float* __restrict__ g3,
                                     const float* __restrict__ be3,
                                     float* __restrict__ o, int c0) {
  const int col = c0 + (threadIdx.x >> 5);
  const int r = threadIdx.x & 31;
  float x[4];
#pragma unroll
  for (int i = 0; i < 4; ++i) {
    const int b = r + 32 * i;
    const float* gib = gi + (size_t)b * 1536;
    const float* ghb = gh + (size_t)b * 1536;
    const float rr = sigmoidf_(gib[col] + ghb[col]);
    const float zt = sigmoidf_(gib[512 + col] + ghb[512 + col]);
    const float nn = tanhf(gib[1024 + col] + rr * ghb[1024 + col]);
    const float hold = h[(size_t)b * H + col];
    const float hnew = (1.f - zt) * nn + zt * hold;
    h[(size_t)b * H + col] = hnew;
    x[i] = lrelu_(hnew);
  }
  float s = x[0] + x[1] + x[2] + x[3];
#pragma unroll
  for (int m = 16; m; m >>= 1) s += __shfl_xor(s, m);
  const float mean = s * (1.f / 128.f);
  float q = 0.f;
#pragma unroll
  for (int i = 0; i < 4; ++i) { const float d = x[i] - mean; q += d * d; }
#pragma unroll
  for (int m = 16; m; m >>= 1) q += __shfl_xor(q, m);
  const float v = q * (1.f / 128.f);
  const float sd = sqrtf(v + BN_EPS);
  const float gc = g3[col], bc = be3[col];
#pragma unroll
  for (int i = 0; i < 4; ++i) {
    const int b = r + 32 * i;
    o[(size_t)b * H + col] = gc * (x[i] - mean) / sd + bc;
  }
}

// --------- softmax + argmax + next-token embedding gather (1 row) ----------
__device__ __forceinline__ void gumbel_row(float* __restrict__ out, int t, int T, int b,
                                           const float* __restrict__ emb,
                                           float* __restrict__ xbuf, float* smem) {
  float* sy = smem;                      // [5000]
  float* red = smem + 5000;              // [256]
  int* redi = (int*)(smem + 5256);       // [256]
  int* swin = (int*)(smem + 5512);       // [1]
  const int tid = threadIdx.x;
  float* row = out + ((size_t)b * T + t) * V_SZ;   // y written by logits stage

  float lmax = -3.4e38f;
  for (int j = tid; j < V_SZ; j += NTHR) {
    const float y = row[j];
    sy[j] = y;
    lmax = fmaxf(lmax, y);
  }
  red[tid] = lmax; __syncthreads();
#pragma unroll
  for (int s = 128; s > 0; s >>= 1) {
    if (tid < s) red[tid] = fmaxf(red[tid], red[tid + s]);
    __syncthreads();
  }
  const float m = red[0];
  __syncthreads();

  float lsum = 0.f;
  for (int j = tid; j < V_SZ; j += NTHR) {
    const float e = expf(sy[j] - m); sy[j] = e; lsum += e;
  }
  red[tid] = lsum; __syncthreads();
#pragma unroll
  for (int s = 128; s > 0; s >>= 1) {
    if (tid < s) red[tid] += red[tid + s];
    __syncthreads();
  }
  const float S = red[0];
  __syncthreads();

  float bmax = -1.f; int bidx = 0x7fffffff;
  for (int j = tid; j < V_SZ; j += NTHR) {
    const float p = sy[j] / S;
    row[j] = p;
    if (p > bmax) { bmax = p; bidx = j; }
  }
  red[tid] = bmax; redi[tid] = bidx; __syncthreads();
#pragma unroll
  for (int s = 128; s > 0; s >>= 1) {
    if (tid < s) {
      const float v2 = red[tid + s]; const int i2 = redi[tid + s];
      if (v2 > red[tid] || (v2 == red[tid] && i2 < redi[tid])) { red[tid] = v2; redi[tid] = i2; }
    }
    __syncthreads();
  }
  if (tid == 0) swin[0] = redi[0];
  __syncthreads();
  const int idx = swin[0];
  const float* er = emb + (size_t)idx * H;
  xbuf[(size_t)b * H + tid] = lrelu_(er[tid]);
  xbuf[(size_t)b * H + NTHR + tid] = lrelu_(er[NTHR + tid]);
}

// ------------------------------ the kernel ---------------------------------
__global__ __launch_bounds__(NTHR, 2) void persist(
    const float* __restrict__ z, const float* __restrict__ temp,
    const float* __restrict__ W_z2h, const float* __restrict__ b_z2h,
    const float* __restrict__ g1, const float* __restrict__ be1,
    const float* __restrict__ emb,
    const float* __restrict__ g2, const float* __restrict__ be2,
    const float* __restrict__ W_ih, const float* __restrict__ b_ih,
    const float* __restrict__ W_hh, const float* __restrict__ b_hh,
    const float* __restrict__ g3, const float* __restrict__ be3,
    const float* __restrict__ W_h2o, const float* __restrict__ b_h2o,
    float* __restrict__ out, float* __restrict__ fws, int T) {
  __shared__ float smem[5552];
  uint32_t* bw = (uint32_t*)(fws + BAR_OFF);
  float* xbuf = fws + XBUF_OFF;
  float* hbuf = fws + H_OFF;
  float* obuf = fws + O_OFF;
  float* si_x = fws + SIX_OFF;
  float* gi   = fws + GI_OFF;
  float* gh   = fws + GH_OFF;
  float* gi_z = fws + GIZ_OFF;
  const int tid = threadIdx.x;
  // slot: pair blocks (i, i+256) (same CU) onto adjacent work indices, so a
  // stage with W workers runs 2 blocks per CU (8 waves) on W/2 CUs.
  const int slot = ((blockIdx.x & 255) << 1) | (blockIdx.x >> 8);
  uint32_t bar = 0;

  // P0: a = lrelu(z @ W_z2h^T + b_z2h) -> xbuf  (64 slots)
  if (slot < 64)
    gemm16x64(z, NOISE_SZ, W_z2h, NOISE_SZ, NOISE_SZ, (slot & 7) * 16, (slot >> 3) * 64,
              b_z2h, nullptr, 0, true, xbuf, H, smem);
  gridbar(bw, ++bar);
  // P1: zbn = BN(a; g1,be1) -> si_x(alias zbn), h0 = zbn
  if (slot < 64) bn8(xbuf, g1, be1, si_x, hbuf, slot * 8);
  gridbar(bw, ++bar);
  // P2: si_z = BN(zbn; g2[512:], be2[512:]) -> obuf
  if (slot < 64) bn8(si_x, g2 + H, be2 + H, obuf, nullptr, slot * 8);
  gridbar(bw, ++bar);
  // P3: gi_z = si_z @ W_ih[:,512:]^T + b_ih (192) || xbuf = lrelu(emb[SOS]) (128)
  if (slot < 192) {
    gemm16x64(obuf, H, W_ih + H, 2 * H, H, (slot & 7) * 16, (slot >> 3) * 64,
              b_ih, nullptr, 0, false, gi_z, 1536, smem);
  } else if (slot < 320) {
    const int b = slot - 192;
    const float* er = emb + (size_t)(V_SZ - 1) * H;
    xbuf[(size_t)b * H + tid] = lrelu_(er[tid]);
    xbuf[(size_t)b * H + NTHR + tid] = lrelu_(er[NTHR + tid]);
  }
  gridbar(bw, ++bar);

  for (int t = 0; t < T; ++t) {
    // SA: gh = h @ W_hh^T + b_hh (384) || si_x = BN(xbuf; g2[:512]) (64)
    if (slot < 384)
      gemm16x32(hbuf, H, W_hh, H, H, (slot & 7) * 16, (slot >> 3) * 32,
                b_hh, nullptr, 0, gh, 1536, smem);
    else if (slot < 448)
      bn8(xbuf, g2, be2, si_x, nullptr, (slot - 384) * 8);
    gridbar(bw, ++bar);
    // SB: gi = si_x @ W_ih[:,:512]^T + gi_z (384)
    if (slot < 384)
      gemm16x32(si_x, H, W_ih, 2 * H, H, (slot & 7) * 16, (slot >> 3) * 32,
                nullptr, gi_z, 1536, gi, 1536, smem);
    gridbar(bw, ++bar);
    // SC: GRU gates + h update + o = BN(lrelu(h)) (64)
    if (slot < 64) gru8(gi, gh, hbuf, g3, be3, obuf, slot * 8);
    gridbar(bw, ++bar);
    // SD: y = (o @ W_h2o^T + b + gumbel)/temp -> out rows (504)
    if (slot < 504)
      gemm16x80_logits(obuf, W_h2o, b_h2o, (slot & 7) * 16, (slot >> 3) * 80,
                       out, t, T, temp, smem);
    gridbar(bw, ++bar);
    // SE: softmax + argmax + gather next embedding (128)
    if (slot < B_SZ) gumbel_row(out, t, T, slot, emb, xbuf, smem);
    gridbar(bw, ++bar);
  }
}

// ---------------------------------------------------------------------------
extern "C" void kernel_launch(void* const* d_in, const int* in_sizes, int n_in,
                              void* d_out, int out_size, void* d_ws, size_t ws_size,
                              hipStream_t stream) {
  const float* z     = (const float*)d_in[0];
  const float* temp  = (const float*)d_in[1];
  const float* W_z2h = (const float*)d_in[3];
  const float* b_z2h = (const float*)d_in[4];
  const float* g1    = (const float*)d_in[5];
  const float* be1   = (const float*)d_in[6];
  const float* emb   = (const float*)d_in[7];
  const float* g2    = (const float*)d_in[8];
  const float* be2   = (const float*)d_in[9];
  const float* W_ih  = (const float*)d_in[10];
  const float* b_ih  = (const float*)d_in[11];
  const float* W_hh  = (const float*)d_in[12];
  const float* b_hh  = (const float*)d_in[13];
  const float* g3    = (const float*)d_in[14];
  const float* be3   = (const float*)d_in[15];
  const float* W_h2o = (const float*)d_in[16];
  const float* b_h2o = (const float*)d_in[17];
  float* out = (float*)d_out;
  float* fws = (float*)d_ws;
  const int T = out_size / (B_SZ * V_SZ);   // 128

  // reset barrier state (generation + 512 flags) for deterministic replay
  hipMemsetAsync((void*)((char*)d_ws + (size_t)BAR_OFF * 4), 0, 40960, stream);
  persist<<<NBLK, NTHR, 0, stream>>>(z, temp, W_z2h, b_z2h, g1, be1, emb, g2, be2,
                                     W_ih, b_ih, W_hh, b_hh, g3, be3, W_h2o, b_h2o,
                                     out, fws, T);
}

// Round 4
// 10739.175 us; speedup vs baseline: 2.4673x; 2.4673x over previous
//
#include <hip/hip_runtime.h>
#include <cstdint>
#include <cstddef>

// ---------------------------------------------------------------------------
// GumbelRNNGenerator multi-kernel v2 (round 4).
// B=128, NOISE=128, H=512, V=5000, T=128 sequential steps, all fp32.
// 4 kernels per step, hardware kernel-boundary sync (no software barriers).
// ---------------------------------------------------------------------------
#define B_SZ 128
#define NOISE_SZ 128
#define H 512
#define V_SZ 5000
#define BN_EPS 1e-5f

// workspace offsets (floats)
#define XBUF_OFF 0            // [128][512] lrelu(emb[prev]) (pre-BN); setup scratch
#define H_OFF    65536        // [128][512] hidden state
#define O_OFF    131072       // [128][512] bn(lrelu(h)); setup: zbn then si_z
#define GI_OFF   196608       // [128][1536]
#define GH_OFF   393216       // [128][1536]
#define GIZ_OFF  589824       // [128][1536] si_z @ W_ih[:,512:]^T + b_ih

// ------------------------------- Threefry ---------------------------------
__device__ __forceinline__ uint32_t rotl32(uint32_t v, int r) {
  return (v << r) | (v >> (32 - r));
}

__device__ __forceinline__ void threefry2x32(uint32_t k0, uint32_t k1,
                                             uint32_t x0, uint32_t x1,
                                             uint32_t& o0, uint32_t& o1) {
  uint32_t k2 = k0 ^ k1 ^ 0x1BD11BDAu;
  x0 += k0; x1 += k1;
#define TFR(r) { x0 += x1; x1 = rotl32(x1, (r)); x1 ^= x0; }
  TFR(13) TFR(15) TFR(26) TFR(6)
  x0 += k1; x1 += k2 + 1u;
  TFR(17) TFR(29) TFR(16) TFR(24)
  x0 += k2; x1 += k0 + 2u;
  TFR(13) TFR(15) TFR(26) TFR(6)
  x0 += k0; x1 += k1 + 3u;
  TFR(17) TFR(29) TFR(16) TFR(24)
  x0 += k1; x1 += k2 + 4u;
  TFR(13) TFR(15) TFR(26) TFR(6)
  x0 += k2; x1 += k0 + 5u;
#undef TFR
  o0 = x0; o1 = x1;
}

// compile-time subkey chain: jax.random.key(42), partitionable fold-in split
struct U2 { uint32_t a, b; };
constexpr U2 tf_c(uint32_t k0, uint32_t k1, uint32_t x0, uint32_t x1) {
  uint32_t k2 = k0 ^ k1 ^ 0x1BD11BDAu;
  x0 += k0; x1 += k1;
#define TFRC(r) { x0 += x1; x1 = (uint32_t)((x1 << (r)) | (x1 >> (32 - (r)))); x1 ^= x0; }
  TFRC(13) TFRC(15) TFRC(26) TFRC(6)
  x0 += k1; x1 += k2 + 1u;
  TFRC(17) TFRC(29) TFRC(16) TFRC(24)
  x0 += k2; x1 += k0 + 2u;
  TFRC(13) TFRC(15) TFRC(26) TFRC(6)
  x0 += k0; x1 += k1 + 3u;
  TFRC(17) TFRC(29) TFRC(16) TFRC(24)
  x0 += k1; x1 += k2 + 4u;
  TFRC(13) TFRC(15) TFRC(26) TFRC(6)
  x0 += k2; x1 += k0 + 5u;
#undef TFRC
  return U2{x0, x1};
}

struct SubKeys { uint32_t v[512]; };
constexpr SubKeys make_subkeys() {
  SubKeys s{};
  uint32_t k0 = 0u, k1 = 42u;
  for (int t = 0; t < 256; ++t) {
    U2 nk = tf_c(k0, k1, 0u, 0u);   // new key
    U2 sb = tf_c(k0, k1, 0u, 1u);   // subkey
    s.v[2 * t] = sb.a; s.v[2 * t + 1] = sb.b;
    k0 = nk.a; k1 = nk.b;
  }
  return s;
}
__device__ __constant__ SubKeys SUBK = make_subkeys();

__device__ __forceinline__ float lrelu_(float x) { return x >= 0.f ? x : 0.2f * x; }
__device__ __forceinline__ float sigmoidf_(float x) {
  return (x >= 0.f) ? 1.f / (1.f + expf(-x)) : expf(x) / (1.f + expf(x));
}

// ------------------------- GEMM 32x64 tile (device fn) ---------------------
// C[m0:+32, n0:+64] = A[32xK]@W[64xK]^T + (full?full:bias), optional lrelu.
__device__ __forceinline__ void gemm32x64(
    const float* __restrict__ A, int lda,
    const float* __restrict__ W, int ldw, int K,
    int m0, int n0,
    const float* __restrict__ bias,
    const float* __restrict__ full, int fullld,
    bool relu,
    float* __restrict__ C, int ldc,
    float* smem) {
  float* As = smem;           // [32][38]
  float* Ws = smem + 1216;    // [32][68]
  const int tid = threadIdx.x;
  const int tn = tid & 15, tm = tid >> 4;
  const int amr = tid >> 3, aq = tid & 7;   // A stager: row, k-quad
  const int wnr = tid >> 2, wq = tid & 3;   // W stager
  float acc[2][4] = {{0.f,0.f,0.f,0.f},{0.f,0.f,0.f,0.f}};
  for (int k0 = 0; k0 < K; k0 += 32) {
    const float4 av = *(const float4*)&A[(size_t)(m0 + amr) * lda + k0 + aq * 4];
    const float4 w0 = *(const float4*)&W[(size_t)(n0 + wnr) * ldw + k0 + wq * 4];
    const float4 w1 = *(const float4*)&W[(size_t)(n0 + wnr) * ldw + k0 + 16 + wq * 4];
    As[(aq * 4 + 0) * 38 + amr] = av.x;
    As[(aq * 4 + 1) * 38 + amr] = av.y;
    As[(aq * 4 + 2) * 38 + amr] = av.z;
    As[(aq * 4 + 3) * 38 + amr] = av.w;
    Ws[(wq * 4 + 0) * 68 + wnr] = w0.x;
    Ws[(wq * 4 + 1) * 68 + wnr] = w0.y;
    Ws[(wq * 4 + 2) * 68 + wnr] = w0.z;
    Ws[(wq * 4 + 3) * 68 + wnr] = w0.w;
    Ws[(16 + wq * 4 + 0) * 68 + wnr] = w1.x;
    Ws[(16 + wq * 4 + 1) * 68 + wnr] = w1.y;
    Ws[(16 + wq * 4 + 2) * 68 + wnr] = w1.z;
    Ws[(16 + wq * 4 + 3) * 68 + wnr] = w1.w;
    __syncthreads();
#pragma unroll
    for (int kk = 0; kk < 32; ++kk) {
      const float2 a2 = *(const float2*)&As[kk * 38 + tm * 2];
      const float4 b4 = *(const float4*)&Ws[kk * 68 + tn * 4];
      acc[0][0] = fmaf(a2.x, b4.x, acc[0][0]);
      acc[0][1] = fmaf(a2.x, b4.y, acc[0][1]);
      acc[0][2] = fmaf(a2.x, b4.z, acc[0][2]);
      acc[0][3] = fmaf(a2.x, b4.w, acc[0][3]);
      acc[1][0] = fmaf(a2.y, b4.x, acc[1][0]);
      acc[1][1] = fmaf(a2.y, b4.y, acc[1][1]);
      acc[1][2] = fmaf(a2.y, b4.z, acc[1][2]);
      acc[1][3] = fmaf(a2.y, b4.w, acc[1][3]);
    }
    __syncthreads();
  }
#pragma unroll
  for (int i = 0; i < 2; ++i) {
    const int m = m0 + tm * 2 + i;
#pragma unroll
    for (int j = 0; j < 4; ++j) {
      const int n = n0 + tn * 4 + j;
      float v = acc[i][j] + (full ? full[(size_t)m * fullld + n] : bias[n]);
      if (relu) v = lrelu_(v);
      C[(size_t)m * ldc + n] = v;
    }
  }
}

// -------------- GEMM 32x80 logits + gumbel epilogue (device fn) ------------
__device__ __forceinline__ void gemm32x80_logits(
    const float* __restrict__ A, const float* __restrict__ W,
    const float* __restrict__ bias, int m0, int n0,
    float* __restrict__ out, int t, int T,
    const float* __restrict__ temp_ptr, float* smem) {
  float* As = smem;            // [32][38]
  float* Ws2 = smem + 1216;    // [32][84]
  const int tid = threadIdx.x;
  const int tn = tid & 15, tm = tid >> 4;
  const int amr = tid >> 3, aq = tid & 7;
  const int wnr = tid >> 2, wq = tid & 3;
  const int pn = 64 + (tid >> 3), pq = tid & 7;   // part-2 stager (tid<128)
  float acc[2][5] = {{0,0,0,0,0},{0,0,0,0,0}};
  for (int k0 = 0; k0 < 512; k0 += 32) {
    const float4 av = *(const float4*)&A[(size_t)(m0 + amr) * 512 + k0 + aq * 4];
    float4 w0 = {0,0,0,0}, w1 = {0,0,0,0}, w2 = {0,0,0,0};
    if (n0 + wnr < V_SZ) {
      w0 = *(const float4*)&W[(size_t)(n0 + wnr) * 512 + k0 + wq * 4];
      w1 = *(const float4*)&W[(size_t)(n0 + wnr) * 512 + k0 + 16 + wq * 4];
    }
    if (tid < 128 && n0 + pn < V_SZ)
      w2 = *(const float4*)&W[(size_t)(n0 + pn) * 512 + k0 + pq * 4];
    As[(aq * 4 + 0) * 38 + amr] = av.x;
    As[(aq * 4 + 1) * 38 + amr] = av.y;
    As[(aq * 4 + 2) * 38 + amr] = av.z;
    As[(aq * 4 + 3) * 38 + amr] = av.w;
    Ws2[(wq * 4 + 0) * 84 + wnr] = w0.x;
    Ws2[(wq * 4 + 1) * 84 + wnr] = w0.y;
    Ws2[(wq * 4 + 2) * 84 + wnr] = w0.z;
    Ws2[(wq * 4 + 3) * 84 + wnr] = w0.w;
    Ws2[(16 + wq * 4 + 0) * 84 + wnr] = w1.x;
    Ws2[(16 + wq * 4 + 1) * 84 + wnr] = w1.y;
    Ws2[(16 + wq * 4 + 2) * 84 + wnr] = w1.z;
    Ws2[(16 + wq * 4 + 3) * 84 + wnr] = w1.w;
    if (tid < 128) {
      Ws2[(pq * 4 + 0) * 84 + pn] = w2.x;
      Ws2[(pq * 4 + 1) * 84 + pn] = w2.y;
      Ws2[(pq * 4 + 2) * 84 + pn] = w2.z;
      Ws2[(pq * 4 + 3) * 84 + pn] = w2.w;
    }
    __syncthreads();
#pragma unroll
    for (int kk = 0; kk < 32; ++kk) {
      const float2 a2 = *(const float2*)&As[kk * 38 + tm * 2];
      const float4 b4 = *(const float4*)&Ws2[kk * 84 + tn * 4];
      const float b1 = Ws2[kk * 84 + 64 + tn];
      acc[0][0] = fmaf(a2.x, b4.x, acc[0][0]);
      acc[0][1] = fmaf(a2.x, b4.y, acc[0][1]);
      acc[0][2] = fmaf(a2.x, b4.z, acc[0][2]);
      acc[0][3] = fmaf(a2.x, b4.w, acc[0][3]);
      acc[0][4] = fmaf(a2.x, b1,   acc[0][4]);
      acc[1][0] = fmaf(a2.y, b4.x, acc[1][0]);
      acc[1][1] = fmaf(a2.y, b4.y, acc[1][1]);
      acc[1][2] = fmaf(a2.y, b4.z, acc[1][2]);
      acc[1][3] = fmaf(a2.y, b4.w, acc[1][3]);
      acc[1][4] = fmaf(a2.y, b1,   acc[1][4]);
    }
    __syncthreads();
  }
  const float temp = temp_ptr[0];
  const uint32_t sk0 = SUBK.v[2 * t], sk1 = SUBK.v[2 * t + 1];
#pragma unroll
  for (int i = 0; i < 2; ++i) {
    const int m = m0 + tm * 2 + i;
    float* rowp = out + ((size_t)m * T + t) * V_SZ;
#pragma unroll
    for (int j = 0; j < 5; ++j) {
      const int n = (j < 4) ? (n0 + tn * 4 + j) : (n0 + 64 + tn);
      if (n < V_SZ) {
        const float logit = acc[i][j] + bias[n];
        uint32_t r0, r1;
        threefry2x32(sk0, sk1, 0u, (uint32_t)(m * V_SZ + n), r0, r1);
        const uint32_t bits = r0 ^ r1;
        const float f = __uint_as_float((bits >> 9) | 0x3f800000u) - 1.0f;
        const float u = fmaxf(1e-20f, f + 1e-20f);
        const float gum = -logf(-logf(u));
        rowp[n] = (logit + gum) / temp;
      }
    }
  }
}

// ----------------- BN over batch, 8 cols per 256-thr block -----------------
__device__ __forceinline__ void bn8(const float* __restrict__ in,
                                    const float* __restrict__ g,
                                    const float* __restrict__ be,
                                    float* __restrict__ outp,
                                    float* __restrict__ out2, int c0) {
  const int col = c0 + (threadIdx.x >> 5);
  const int r = threadIdx.x & 31;
  float x0 = in[(size_t)r * H + col];
  float x1 = in[(size_t)(r + 32) * H + col];
  float x2 = in[(size_t)(r + 64) * H + col];
  float x3 = in[(size_t)(r + 96) * H + col];
  float s = x0 + x1 + x2 + x3;
#pragma unroll
  for (int m = 16; m; m >>= 1) s += __shfl_xor(s, m);
  const float mean = s * (1.f / 128.f);
  const float d0 = x0 - mean, d1 = x1 - mean, d2 = x2 - mean, d3 = x3 - mean;
  float q = d0 * d0 + d1 * d1 + d2 * d2 + d3 * d3;
#pragma unroll
  for (int m = 16; m; m >>= 1) q += __shfl_xor(q, m);
  const float v = q * (1.f / 128.f);
  const float sd = sqrtf(v + BN_EPS);
  const float gc = g[col], bc = be[col];
  const float y0 = gc * d0 / sd + bc;
  const float y1 = gc * d1 / sd + bc;
  const float y2 = gc * d2 / sd + bc;
  const float y3 = gc * d3 / sd + bc;
  outp[(size_t)r * H + col] = y0;
  outp[(size_t)(r + 32) * H + col] = y1;
  outp[(size_t)(r + 64) * H + col] = y2;
  outp[(size_t)(r + 96) * H + col] = y3;
  if (out2) {
    out2[(size_t)r * H + col] = y0;
    out2[(size_t)(r + 32) * H + col] = y1;
    out2[(size_t)(r + 64) * H + col] = y2;
    out2[(size_t)(r + 96) * H + col] = y3;
  }
}

// ================================ kernels ==================================

// setup 1: a = lrelu(z @ W_z2h^T + b_z2h) -> xbuf   (32 blocks x 256)
__global__ __launch_bounds__(256, 2) void k_z2h(const float* __restrict__ z,
                                                const float* __restrict__ W,
                                                const float* __restrict__ bias,
                                                float* __restrict__ fws) {
  __shared__ float smem[3392];
  gemm32x64(z, NOISE_SZ, W, NOISE_SZ, NOISE_SZ,
            ((int)blockIdx.x & 3) * 32, ((int)blockIdx.x >> 2) * 64,
            bias, nullptr, 0, true, fws + XBUF_OFF, H, smem);
}

// setup 2: zbn = BN(a; g1,be1) -> obuf, h0 -> hbuf   (64 blocks x 256)
__global__ __launch_bounds__(256, 2) void k_bn1(const float* __restrict__ g1,
                                                const float* __restrict__ be1,
                                                float* __restrict__ fws) {
  bn8(fws + XBUF_OFF, g1, be1, fws + O_OFF, fws + H_OFF, (int)blockIdx.x * 8);
}

// setup 3: si_z = BN(zbn; g2[512:],be2[512:]) in place in obuf  (64 blocks)
__global__ __launch_bounds__(256, 2) void k_bn2(const float* __restrict__ g2,
                                                const float* __restrict__ be2,
                                                float* __restrict__ fws) {
  bn8(fws + O_OFF, g2 + H, be2 + H, fws + O_OFF, nullptr, (int)blockIdx.x * 8);
}

// setup 4: gi_z GEMM (96) || gh0 GEMM (96) || xbuf0 = lrelu(emb[SOS]) (128)
__global__ __launch_bounds__(256, 2) void k_setup4(
    const float* __restrict__ W_ih, const float* __restrict__ b_ih,
    const float* __restrict__ W_hh, const float* __restrict__ b_hh,
    const float* __restrict__ emb, float* __restrict__ fws) {
  __shared__ float smem[3392];
  const int blk = blockIdx.x;
  if (blk < 96) {
    gemm32x64(fws + O_OFF, H, W_ih + H, 2 * H, H,
              (blk & 3) * 32, (blk >> 2) * 64,
              b_ih, nullptr, 0, false, fws + GIZ_OFF, 1536, smem);
  } else if (blk < 192) {
    const int b2 = blk - 96;
    gemm32x64(fws + H_OFF, H, W_hh, H, H,
              (b2 & 3) * 32, (b2 >> 2) * 64,
              b_hh, nullptr, 0, false, fws + GH_OFF, 1536, smem);
  } else {
    const int b = blk - 192;
    const int tid = threadIdx.x;
    const float* er = emb + (size_t)(V_SZ - 1) * H;
    float* xbuf = fws + XBUF_OFF;
    xbuf[(size_t)b * H + tid] = lrelu_(er[tid]);
    xbuf[(size_t)b * H + 256 + tid] = lrelu_(er[256 + tid]);
  }
}

// step B: inline BN(xbuf; g2[:512],be2[:512]) + gi = si_x @ W_ih[:,:512]^T + gi_z
// 96 blocks x 256 threads
__global__ __launch_bounds__(256, 2) void k_gi(
    const float* __restrict__ g2, const float* __restrict__ be2,
    const float* __restrict__ W_ih, float* __restrict__ fws) {
  __shared__ float sc[512];
  __shared__ float sh[512];
  __shared__ float smem[3392];
  const float* xbuf = fws + XBUF_OFF;
  const float* gi_z = fws + GIZ_OFF;
  float* gi = fws + GI_OFF;
  const int tid = threadIdx.x;

  // phase 1: column stats (2 cols/thread, fp64 accum; deterministic)
  {
    const int c = tid * 2;
    double s0 = 0.0, s1 = 0.0, q0 = 0.0, q1 = 0.0;
    for (int r = 0; r < 128; ++r) {
      const float2 v = *(const float2*)&xbuf[(size_t)r * H + c];
      s0 += v.x; s1 += v.y;
      q0 += (double)v.x * v.x; q1 += (double)v.y * v.y;
    }
    const double m0 = s0 * (1.0 / 128.0), m1 = s1 * (1.0 / 128.0);
    const double v0 = q0 * (1.0 / 128.0) - m0 * m0;
    const double v1 = q1 * (1.0 / 128.0) - m1 * m1;
    const float sd0 = sqrtf((float)v0 + BN_EPS);
    const float sd1 = sqrtf((float)v1 + BN_EPS);
    const float s0f = g2[c] / sd0, s1f = g2[c + 1] / sd1;
    sc[c] = s0f; sc[c + 1] = s1f;
    sh[c] = be2[c] - (float)m0 * s0f;
    sh[c + 1] = be2[c + 1] - (float)m1 * s1f;
  }
  __syncthreads();

  // phase 2: 32x64 GEMM with A = xbuf*sc + sh staged on the fly
  float* As = smem;           // [32][38]
  float* Ws = smem + 1216;    // [32][68]
  const int blk = blockIdx.x;
  const int m0 = (blk & 3) * 32, n0 = (blk >> 2) * 64;
  const int tn = tid & 15, tm = tid >> 4;
  const int amr = tid >> 3, aq = tid & 7;
  const int wnr = tid >> 2, wq = tid & 3;
  float acc[2][4] = {{0.f,0.f,0.f,0.f},{0.f,0.f,0.f,0.f}};
  for (int k0 = 0; k0 < 512; k0 += 32) {
    float4 av = *(const float4*)&xbuf[(size_t)(m0 + amr) * H + k0 + aq * 4];
    const float4 s4 = *(const float4*)&sc[k0 + aq * 4];
    const float4 h4 = *(const float4*)&sh[k0 + aq * 4];
    av.x = fmaf(av.x, s4.x, h4.x);
    av.y = fmaf(av.y, s4.y, h4.y);
    av.z = fmaf(av.z, s4.z, h4.z);
    av.w = fmaf(av.w, s4.w, h4.w);
    const float4 w0 = *(const float4*)&W_ih[(size_t)(n0 + wnr) * 1024 + k0 + wq * 4];
    const float4 w1 = *(const float4*)&W_ih[(size_t)(n0 + wnr) * 1024 + k0 + 16 + wq * 4];
    As[(aq * 4 + 0) * 38 + amr] = av.x;
    As[(aq * 4 + 1) * 38 + amr] = av.y;
    As[(aq * 4 + 2) * 38 + amr] = av.z;
    As[(aq * 4 + 3) * 38 + amr] = av.w;
    Ws[(wq * 4 + 0) * 68 + wnr] = w0.x;
    Ws[(wq * 4 + 1) * 68 + wnr] = w0.y;
    Ws[(wq * 4 + 2) * 68 + wnr] = w0.z;
    Ws[(wq * 4 + 3) * 68 + wnr] = w0.w;
    Ws[(16 + wq * 4 + 0) * 68 + wnr] = w1.x;
    Ws[(16 + wq * 4 + 1) * 68 + wnr] = w1.y;
    Ws[(16 + wq * 4 + 2) * 68 + wnr] = w1.z;
    Ws[(16 + wq * 4 + 3) * 68 + wnr] = w1.w;
    __syncthreads();
#pragma unroll
    for (int kk = 0; kk < 32; ++kk) {
      const float2 a2 = *(const float2*)&As[kk * 38 + tm * 2];
      const float4 b4 = *(const float4*)&Ws[kk * 68 + tn * 4];
      acc[0][0] = fmaf(a2.x, b4.x, acc[0][0]);
      acc[0][1] = fmaf(a2.x, b4.y, acc[0][1]);
      acc[0][2] = fmaf(a2.x, b4.z, acc[0][2]);
      acc[0][3] = fmaf(a2.x, b4.w, acc[0][3]);
      acc[1][0] = fmaf(a2.y, b4.x, acc[1][0]);
      acc[1][1] = fmaf(a2.y, b4.y, acc[1][1]);
      acc[1][2] = fmaf(a2.y, b4.z, acc[1][2]);
      acc[1][3] = fmaf(a2.y, b4.w, acc[1][3]);
    }
    __syncthreads();
  }
#pragma unroll
  for (int i = 0; i < 2; ++i) {
    const int m = m0 + tm * 2 + i;
#pragma unroll
    for (int j = 0; j < 4; ++j) {
      const int n = n0 + tn * 4 + j;
      gi[(size_t)m * 1536 + n] = acc[i][j] + gi_z[(size_t)m * 1536 + n];
    }
  }
}

// step C: GRU gates + h update + o = BN(lrelu(h))   (128 blocks x 128 thr)
__global__ __launch_bounds__(128, 4) void k_gru(
    const float* __restrict__ g3, const float* __restrict__ be3,
    float* __restrict__ fws) {
  const float* gi = fws + GI_OFF;
  const float* gh = fws + GH_OFF;
  float* h = fws + H_OFF;
  float* o = fws + O_OFF;
  const int col = (int)blockIdx.x * 4 + ((int)threadIdx.x >> 5);
  const int r = threadIdx.x & 31;
  float x[4];
#pragma unroll
  for (int i = 0; i < 4; ++i) {
    const int b = r + 32 * i;
    const float* gib = gi + (size_t)b * 1536;
    const float* ghb = gh + (size_t)b * 1536;
    const float rr = sigmoidf_(gib[col] + ghb[col]);
    const float zt = sigmoidf_(gib[512 + col] + ghb[512 + col]);
    const float nn = tanhf(gib[1024 + col] + rr * ghb[1024 + col]);
    const float hold = h[(size_t)b * H + col];
    const float hnew = (1.f - zt) * nn + zt * hold;
    h[(size_t)b * H + col] = hnew;
    x[i] = lrelu_(hnew);
  }
  float s = x[0] + x[1] + x[2] + x[3];
#pragma unroll
  for (int m = 16; m; m >>= 1) s += __shfl_xor(s, m);
  const float mean = s * (1.f / 128.f);
  float q = 0.f;
#pragma unroll
  for (int i = 0; i < 4; ++i) { const float d = x[i] - mean; q += d * d; }
#pragma unroll
  for (int m = 16; m; m >>= 1) q += __shfl_xor(q, m);
  const float v = q * (1.f / 128.f);
  const float sd = sqrtf(v + BN_EPS);
  const float gc = g3[col], bc = be3[col];
#pragma unroll
  for (int i = 0; i < 4; ++i) {
    const int b = r + 32 * i;
    o[(size_t)b * H + col] = gc * (x[i] - mean) / sd + bc;
  }
}

// step D: y = (o@W_h2o^T + b + gumbel)/temp -> out (252 blk) || gh_next (96 blk)
__global__ __launch_bounds__(256, 2) void k_logits_gh(
    const float* __restrict__ W_h2o, const float* __restrict__ b_h2o,
    const float* __restrict__ W_hh, const float* __restrict__ b_hh,
    const float* __restrict__ temp, float* __restrict__ out,
    float* __restrict__ fws, int t, int T) {
  __shared__ float smem[3904];
  const int blk = blockIdx.x;
  if (blk < 252) {
    gemm32x80_logits(fws + O_OFF, W_h2o, b_h2o,
                     (blk & 3) * 32, (blk >> 2) * 80, out, t, T, temp, smem);
  } else {
    const int b2 = blk - 252;
    gemm32x64(fws + H_OFF, H, W_hh, H, H,
              (b2 & 3) * 32, (b2 >> 2) * 64,
              b_hh, nullptr, 0, false, fws + GH_OFF, 1536, smem);
  }
}

// step E: softmax + argmax + gather next embedding  (128 blocks x 256 thr)
__global__ __launch_bounds__(256, 2) void k_gumbel(
    float* __restrict__ out, const float* __restrict__ emb,
    float* __restrict__ fws, int t, int T) {
  __shared__ float sy[V_SZ];
  __shared__ float red[256];
  __shared__ int redi[256];
  __shared__ int swin[1];
  float* xbuf = fws + XBUF_OFF;
  const int b = blockIdx.x;
  const int tid = threadIdx.x;
  float* row = out + ((size_t)b * T + t) * V_SZ;

  float lmax = -3.4e38f;
  for (int j = tid; j < V_SZ; j += 256) {
    const float y = row[j];
    sy[j] = y;
    lmax = fmaxf(lmax, y);
  }
  red[tid] = lmax; __syncthreads();
#pragma unroll
  for (int s = 128; s > 0; s >>= 1) {
    if (tid < s) red[tid] = fmaxf(red[tid], red[tid + s]);
    __syncthreads();
  }
  const float m = red[0];
  __syncthreads();

  float lsum = 0.f;
  for (int j = tid; j < V_SZ; j += 256) {
    const float e = expf(sy[j] - m); sy[j] = e; lsum += e;
  }
  red[tid] = lsum; __syncthreads();
#pragma unroll
  for (int s = 128; s > 0; s >>= 1) {
    if (tid < s) red[tid] += red[tid + s];
    __syncthreads();
  }
  const float S = red[0];
  __syncthreads();

  float bmax = -1.f; int bidx = 0x7fffffff;
  for (int j = tid; j < V_SZ; j += 256) {
    const float p = sy[j] / S;
    row[j] = p;
    if (p > bmax) { bmax = p; bidx = j; }
  }
  red[tid] = bmax; redi[tid] = bidx; __syncthreads();
#pragma unroll
  for (int s = 128; s > 0; s >>= 1) {
    if (tid < s) {
      const float v2 = red[tid + s]; const int i2 = redi[tid + s];
      if (v2 > red[tid] || (v2 == red[tid] && i2 < redi[tid])) { red[tid] = v2; redi[tid] = i2; }
    }
    __syncthreads();
  }
  if (tid == 0) swin[0] = redi[0];
  __syncthreads();
  const int idx = swin[0];
  const float* er = emb + (size_t)idx * H;
  xbuf[(size_t)b * H + tid] = lrelu_(er[tid]);
  xbuf[(size_t)b * H + 256 + tid] = lrelu_(er[256 + tid]);
}

// ---------------------------------------------------------------------------
extern "C" void kernel_launch(void* const* d_in, const int* in_sizes, int n_in,
                              void* d_out, int out_size, void* d_ws, size_t ws_size,
                              hipStream_t stream) {
  const float* z     = (const float*)d_in[0];
  const float* temp  = (const float*)d_in[1];
  const float* W_z2h = (const float*)d_in[3];
  const float* b_z2h = (const float*)d_in[4];
  const float* g1    = (const float*)d_in[5];
  const float* be1   = (const float*)d_in[6];
  const float* emb   = (const float*)d_in[7];
  const float* g2    = (const float*)d_in[8];
  const float* be2   = (const float*)d_in[9];
  const float* W_ih  = (const float*)d_in[10];
  const float* b_ih  = (const float*)d_in[11];
  const float* W_hh  = (const float*)d_in[12];
  const float* b_hh  = (const float*)d_in[13];
  const float* g3    = (const float*)d_in[14];
  const float* be3   = (const float*)d_in[15];
  const float* W_h2o = (const float*)d_in[16];
  const float* b_h2o = (const float*)d_in[17];
  float* out = (float*)d_out;
  float* fws = (float*)d_ws;
  const int T = out_size / (B_SZ * V_SZ);   // 128

  // ---- setup ----
  k_z2h<<<32, 256, 0, stream>>>(z, W_z2h, b_z2h, fws);
  k_bn1<<<64, 256, 0, stream>>>(g1, be1, fws);
  k_bn2<<<64, 256, 0, stream>>>(g2, be2, fws);
  k_setup4<<<320, 256, 0, stream>>>(W_ih, b_ih, W_hh, b_hh, emb, fws);

  // ---- steps ----
  for (int t = 0; t < T; ++t) {
    k_gi<<<96, 256, 0, stream>>>(g2, be2, W_ih, fws);
    k_gru<<<128, 128, 0, stream>>>(g3, be3, fws);
    k_logits_gh<<<348, 256, 0, stream>>>(W_h2o, b_h2o, W_hh, b_hh, temp, out, fws, t, T);
    k_gumbel<<<128, 256, 0, stream>>>(out, emb, fws, t, T);
  }
}